// Round 2
// baseline (494.267 us; speedup 1.0000x reference)
//
#include <hip/hip_runtime.h>
#include <hip/hip_bf16.h>
#include <cstdint>

// SpatialAttentionModule: x[4,256,64,64] fp32; q=Wq x, k=Wk x, v=Wv x (1x1 conv);
// energy = q^T k per batch (N=4096), softmax over j, out = gamma * (v @ attn^T) + x.
//
// Round-2: split-bf16 precision. Every fp32 on the Q/K path is stored as
// hi|lo bf16 pair concatenated along the contraction dim (K=512). A single
// MFMA chain over K=512 computes the full (qh+ql)(kh+kl) product with fp32
// accumulation -> ~2^-18 relative logit error (round-1's plain bf16 gave
// ~0.13 logit noise -> 0.109 absmax, just over the 0.1025 threshold).
//   k_prep_xs : x [B][C][N] fp32 -> xs [B*N][512] bf16 (hi|lo, LDS transpose)
//   k_cast_ws : Wq|Wk|Wv fp32 -> Ws [3*256][512] bf16 (hi|lo)
//   k_proj    : Qs,Ks [B*N][512] split-bf16 ; V [B*C][N] bf16 (K=512 MFMA)
//   k_attn    : two-pass softmax attention; phase-1 max from hi*hi only.
// MFMA layouts (HW-verified, learn_hip m89/m91):
//   A[m=lane&15][k=quad*8+j], B[k=quad*8+j][n=lane&15], C/D: col=lane&15, row=quad*4+reg.

#define C_DIM 256
#define CK 512          // split contraction dim (hi 0..255 | lo 256..511)
#define N_DIM 4096
#define B_DIM 4

typedef short bf16x8 __attribute__((ext_vector_type(8)));
typedef float f32x4  __attribute__((ext_vector_type(4)));

__device__ __forceinline__ unsigned short f2bf(float f) {
  union { float f; unsigned u; } v; v.f = f;
  unsigned r = v.u + 0x7fffu + ((v.u >> 16) & 1u);   // round-to-nearest-even
  return (unsigned short)(r >> 16);
}
__device__ __forceinline__ float bf2f(unsigned short h) {
  union { unsigned u; float f; } v; v.u = ((unsigned)h) << 16;
  return v.f;
}

// ---------------- prep: transpose-cast x -> xs split-bf16 [B*N][512] ----------------
__global__ __launch_bounds__(256) void k_prep_xs(const float* __restrict__ x,
                                                 unsigned short* __restrict__ xs) {
  __shared__ float tile[64][65];
  const int b = blockIdx.z, nb = blockIdx.x * 64, cb = blockIdx.y * 64;
  const float* xb = x + (size_t)b * C_DIM * N_DIM;
  for (int i = threadIdx.x; i < 64 * 64; i += 256) {
    int c = i >> 6, n = i & 63;
    tile[c][n] = xb[(size_t)(cb + c) * N_DIM + nb + n];
  }
  __syncthreads();
  unsigned short* xsb = xs + (size_t)b * N_DIM * CK;
  for (int i = threadIdx.x; i < 64 * 64; i += 256) {
    int n = i >> 6, c = i & 63;
    float v = tile[c][n];
    unsigned short hi = f2bf(v);
    unsigned short lo = f2bf(v - bf2f(hi));
    unsigned short* row = xsb + (size_t)(nb + n) * CK + cb + c;
    row[0] = hi;
    row[256] = lo;
  }
}

// ---------------- prep: split-cast 3 weight matrices -> Ws [3*256][512] ----------------
__global__ __launch_bounds__(256) void k_cast_ws(const float* __restrict__ Wq,
                                                 const float* __restrict__ Wk,
                                                 const float* __restrict__ Wv,
                                                 unsigned short* __restrict__ Ws) {
  int i = blockIdx.x * 256 + threadIdx.x;          // 0 .. 3*65536-1
  int sel = i >> 16, j = i & 65535;
  int o = j >> 8, c = j & 255;
  const float* s = (sel == 0) ? Wq : (sel == 1) ? Wk : Wv;
  float v = s[j];
  unsigned short hi = f2bf(v);
  unsigned short lo = f2bf(v - bf2f(hi));
  unsigned short* row = Ws + (size_t)(sel * 256 + o) * CK + c;
  row[0] = hi;
  row[256] = lo;
}

// ---------------- QKV projection GEMMs (K=512 split) ----------------
// z=0: Qs[g][:]  split-bf16 of q[g][o] = sum_c Wq[o][c] x[g][c] + bq[o]
// z=1: Ks same with Wk/bk
// z=2: V[b][o][j] bf16 of sum_c Wv[o][c] x[b][c][j] + bv[o]   (layout [B*C][N])
__global__ __launch_bounds__(256) void k_proj(const unsigned short* __restrict__ xs,
                                              const unsigned short* __restrict__ Ws,
                                              const float* __restrict__ bq,
                                              const float* __restrict__ bk,
                                              const float* __restrict__ bv,
                                              unsigned short* __restrict__ Qs,
                                              unsigned short* __restrict__ Ks,
                                              unsigned short* __restrict__ Vc) {
  const int z = blockIdx.y;
  const int w = threadIdx.x >> 6, lane = threadIdx.x & 63;
  const int quad = lane >> 4, li = lane & 15;
  const unsigned short* W = Ws + (size_t)z * 256 * CK;
  const float* bias = (z == 0) ? bq : (z == 1) ? bk : bv;

  if (z < 2) {
    unsigned short* out = (z == 0) ? Qs : Ks;
    const int g0 = (blockIdx.x * 4 + w) * 16;
    bf16x8 a[16];
    const unsigned short* arow = xs + (size_t)(g0 + li) * CK + quad * 8;
#pragma unroll
    for (int kf = 0; kf < 16; kf++) a[kf] = *(const bf16x8*)(arow + kf * 32);
    for (int ot = 0; ot < 16; ot++) {
      f32x4 acc = {0.f, 0.f, 0.f, 0.f};
      const unsigned short* brow = W + (size_t)(ot * 16 + li) * CK + quad * 8;
#pragma unroll
      for (int kf = 0; kf < 16; kf++) {
        bf16x8 bf = *(const bf16x8*)(brow + kf * 32);
        acc = __builtin_amdgcn_mfma_f32_16x16x32_bf16(a[kf], bf, acc, 0, 0, 0);
      }
      float bb = bias[ot * 16 + li];
      unsigned short* orow = out + (size_t)g0 * CK + ot * 16 + li;
#pragma unroll
      for (int r = 0; r < 4; r++) {
        float val = acc[r] + bb;
        unsigned short hi = f2bf(val);
        unsigned short lo = f2bf(val - bf2f(hi));
        orow[(size_t)(quad * 4 + r) * CK] = hi;
        orow[(size_t)(quad * 4 + r) * CK + 256] = lo;
      }
    }
  } else {
    const int t = blockIdx.x * 4 + w;
    const int b = t >> 8, j0 = (t & 255) * 16;
    bf16x8 bfr[16];
    const unsigned short* brow = xs + (size_t)(b * N_DIM + j0 + li) * CK + quad * 8;
#pragma unroll
    for (int kf = 0; kf < 16; kf++) bfr[kf] = *(const bf16x8*)(brow + kf * 32);
    for (int ot = 0; ot < 16; ot++) {
      f32x4 acc = {0.f, 0.f, 0.f, 0.f};
      const unsigned short* arow = W + (size_t)(ot * 16 + li) * CK + quad * 8;
#pragma unroll
      for (int kf = 0; kf < 16; kf++) {
        bf16x8 af = *(const bf16x8*)(arow + kf * 32);
        acc = __builtin_amdgcn_mfma_f32_16x16x32_bf16(af, bfr[kf], acc, 0, 0, 0);
      }
      unsigned short* obase = Vc + ((size_t)(b * C_DIM + ot * 16 + quad * 4)) * N_DIM + j0 + li;
#pragma unroll
      for (int r = 0; r < 4; r++) {
        float bb = bias[ot * 16 + quad * 4 + r];
        obase[(size_t)r * N_DIM] = f2bf(acc[r] + bb);
      }
    }
  }
}

// ---------------- fused attention ----------------
// grid (64,4): x = 64-row block, y = batch. 4 waves x 16 rows each.
// Phase 1: approx row max from hi*hi (K-hi staged in LDS, JT1=64 rows).
// Phase 2: full split S (K=512), P=exp2, l from bf16-rounded P, O^T += V*P^T.
#define JT1 64
#define JT2 32
#define KSTR1 264   // phase-1 K-hi row: 256 data + 8 pad (row = 528B, 4-bank shift)
#define KSTR2 520   // phase-2 K row: 512 data + 8 pad (row = 1040B, 4-bank shift)
#define VSTR 40
#define PSTR 40
// LDS (ushorts): phase2 = 32*520 + 256*40 + 4*16*40 = 29440 (58.9 KB); phase1 = 64*264 fits.
#define SMEM_US 29440

__global__ __launch_bounds__(256) void k_attn(const unsigned short* __restrict__ Qs,
                                              const unsigned short* __restrict__ Ks,
                                              const unsigned short* __restrict__ Vc,
                                              const float* __restrict__ x,
                                              const float* __restrict__ gamma_p,
                                              float* __restrict__ out) {
  __shared__ __align__(16) unsigned short smem[SMEM_US];
  const int b = blockIdx.y;
  const int w = threadIdx.x >> 6, lane = threadIdx.x & 63;
  const int quad = lane >> 4, li = lane & 15;
  const int ibase = blockIdx.x * 64 + w * 16;

  // Q fragments (B-operand: n=i, k over 512 split channels); kf 0..7 = hi half
  bf16x8 qf[16];
  {
    const unsigned short* qrow = Qs + (size_t)(b * N_DIM + ibase + li) * CK + quad * 8;
#pragma unroll
    for (int kf = 0; kf < 16; kf++) qf[kf] = *(const bf16x8*)(qrow + kf * 32);
  }
  const unsigned short* Kb = Ks + (size_t)b * N_DIM * CK;
  const unsigned short* Vb = Vc + (size_t)b * C_DIM * N_DIM;

  // ---- phase 1: row max from hi*hi only (enough accuracy for the exp shift) ----
  float m = -3.0e38f;
  for (int jt = 0; jt < N_DIM; jt += JT1) {
    __syncthreads();
    {
      // 64 rows x 512B (hi half) = 2048 float4
      for (int it = 0; it < 8; it++) {
        int idx = it * 256 + threadIdx.x;
        int j = idx >> 5, u = idx & 31;
        *(float4*)(smem + j * KSTR1 + u * 8) =
            *(const float4*)(Kb + (size_t)(jt + j) * CK + u * 8);
      }
    }
    __syncthreads();
#pragma unroll
    for (int sub = 0; sub < 4; sub++) {
      f32x4 s = {0.f, 0.f, 0.f, 0.f};
      const unsigned short* krow = smem + (sub * 16 + li) * KSTR1 + quad * 8;
#pragma unroll
      for (int kf = 0; kf < 8; kf++) {
        bf16x8 kf8 = *(const bf16x8*)(krow + kf * 32);
        s = __builtin_amdgcn_mfma_f32_16x16x32_bf16(kf8, qf[kf], s, 0, 0, 0);
      }
      m = fmaxf(m, fmaxf(fmaxf(s[0], s[1]), fmaxf(s[2], s[3])));
    }
  }
  m = fmaxf(m, __shfl_xor(m, 16));
  m = fmaxf(m, __shfl_xor(m, 32));   // all lanes: max for col i = lane&15

  // ---- phase 2: full-precision S, exp, PV ----
  const float LOG2E = 1.4426950408889634f;
  float l = 0.0f;
  f32x4 acc[16];
#pragma unroll
  for (int ct = 0; ct < 16; ct++) acc[ct] = (f32x4){0.f, 0.f, 0.f, 0.f};

  unsigned short* K_lds = smem;                        // [32][KSTR2]
  unsigned short* V_lds = smem + 32 * KSTR2;           // [256][VSTR]
  unsigned short* P_lds = smem + 32 * KSTR2 + 256 * VSTR + w * 16 * PSTR;  // per-wave

  for (int jt = 0; jt < N_DIM; jt += JT2) {
    __syncthreads();
    {
      // K: 32 rows x 1024B = 2048 float4
      for (int it = 0; it < 8; it++) {
        int idx = it * 256 + threadIdx.x;
        int j = idx >> 6, u = idx & 63;
        *(float4*)(K_lds + j * KSTR2 + u * 8) =
            *(const float4*)(Kb + (size_t)(jt + j) * CK + u * 8);
      }
      // V: 256 rows x 64B = 1024 float4
      const unsigned short* vsrc = Vb + (size_t)jt;
      for (int it = 0; it < 4; it++) {
        int idx = it * 256 + threadIdx.x;
        int c = idx >> 2, u = idx & 3;
        *(float4*)(V_lds + c * VSTR + u * 8) = *(const float4*)(vsrc + (size_t)c * N_DIM + u * 8);
      }
    }
    __syncthreads();

    // S^T tiles: rows j (quad*4+reg), cols i (lane&15); K=512 split channels
#pragma unroll
    for (int sub = 0; sub < 2; sub++) {
      f32x4 s = {0.f, 0.f, 0.f, 0.f};
      const unsigned short* krow = K_lds + (sub * 16 + li) * KSTR2 + quad * 8;
#pragma unroll
      for (int kf = 0; kf < 16; kf++) {
        bf16x8 kf8 = *(const bf16x8*)(krow + kf * 32);
        s = __builtin_amdgcn_mfma_f32_16x16x32_bf16(kf8, qf[kf], s, 0, 0, 0);
      }
      float p0 = exp2f((s[0] - m) * LOG2E);
      float p1 = exp2f((s[1] - m) * LOG2E);
      float p2 = exp2f((s[2] - m) * LOG2E);
      float p3 = exp2f((s[3] - m) * LOG2E);
      unsigned short h0 = f2bf(p0), h1 = f2bf(p1), h2 = f2bf(p2), h3 = f2bf(p3);
      // l sums the bf16-rounded P actually used by PV -> consistent normalization
      l += (bf2f(h0) + bf2f(h1)) + (bf2f(h2) + bf2f(h3));
      unsigned u0 = (unsigned)h0 | ((unsigned)h1 << 16);
      unsigned u1 = (unsigned)h2 | ((unsigned)h3 << 16);
      *(uint2*)(P_lds + li * PSTR + sub * 16 + quad * 4) = make_uint2(u0, u1);
    }
    // P as B-operand (n=i, k=j): contiguous 16B per lane
    bf16x8 pf = *(const bf16x8*)(P_lds + li * PSTR + quad * 8);
#pragma unroll
    for (int ct = 0; ct < 16; ct++) {
      bf16x8 vf = *(const bf16x8*)(V_lds + (ct * 16 + li) * VSTR + quad * 8);
      acc[ct] = __builtin_amdgcn_mfma_f32_16x16x32_bf16(vf, pf, acc[ct], 0, 0, 0);
    }
  }

  l += __shfl_xor(l, 16);
  l += __shfl_xor(l, 32);           // all lanes: sum for col i = lane&15
  const float scale = gamma_p[0] / l;

  const float* xb = x + (size_t)b * C_DIM * N_DIM;
  float* ob = out + (size_t)b * C_DIM * N_DIM;
  const int icol = ibase + li;
#pragma unroll
  for (int ct = 0; ct < 16; ct++) {
#pragma unroll
    for (int r = 0; r < 4; r++) {
      size_t off = (size_t)(ct * 16 + quad * 4 + r) * N_DIM + icol;
      ob[off] = acc[ct][r] * scale + xb[off];
    }
  }
}

extern "C" void kernel_launch(void* const* d_in, const int* in_sizes, int n_in,
                              void* d_out, int out_size, void* d_ws, size_t ws_size,
                              hipStream_t stream) {
  const float* x     = (const float*)d_in[0];
  const float* Wq    = (const float*)d_in[1];
  const float* bq    = (const float*)d_in[2];
  const float* Wk    = (const float*)d_in[3];
  const float* bk    = (const float*)d_in[4];
  const float* Wv    = (const float*)d_in[5];
  const float* bv    = (const float*)d_in[6];
  const float* gamma = (const float*)d_in[7];
  float* out = (float*)d_out;

  // workspace: xs 16MB | Qs 16MB | Ks 16MB | V 8MB | Ws 768KB  (~56.75 MB)
  char* ws = (char*)d_ws;
  unsigned short* xs = (unsigned short*)(ws);
  unsigned short* Qs = (unsigned short*)(ws + (size_t)16 * 1024 * 1024);
  unsigned short* Ksp= (unsigned short*)(ws + (size_t)32 * 1024 * 1024);
  unsigned short* Vc = (unsigned short*)(ws + (size_t)48 * 1024 * 1024);
  unsigned short* Wsp= (unsigned short*)(ws + (size_t)56 * 1024 * 1024);

  k_prep_xs<<<dim3(64, 4, 4), 256, 0, stream>>>(x, xs);
  k_cast_ws<<<dim3(768), 256, 0, stream>>>(Wq, Wk, Wv, Wsp);
  k_proj<<<dim3(256, 3), 256, 0, stream>>>(xs, Wsp, bq, bk, bv, Qs, Ksp, Vc);
  k_attn<<<dim3(64, 4), 256, 0, stream>>>(Qs, Ksp, Vc, x, gamma, out);
}